// Round 8
// baseline (817.821 us; speedup 1.0000x reference)
//
#include <hip/hip_runtime.h>
#include <hip/hip_bf16.h>
#include <cstdint>

#define DEVINL __device__ __forceinline__

typedef __attribute__((ext_vector_type(8))) short bf16x8;
typedef __attribute__((ext_vector_type(4))) float f32x4;

DEVINL unsigned short f2bf(float f) {
    union { float f; unsigned u; } v; v.f = f;
    unsigned r = v.u + 0x7fffu + ((v.u >> 16) & 1u);   // RNE
    return (unsigned short)(r >> 16);
}
DEVINL float bf2f(unsigned short h) {
    union { unsigned u; float f; } v; v.u = ((unsigned)h) << 16;
    return v.f;
}

constexpr int BM = 64, BN = 256, BK = 32;
constexpr int PA  = 40;     // sA pitch (u16)
constexpr int NSP = 256;    // H*W

// Per-sample activation arena (u16 elements), stride 2 MiB.
constexpr size_t ARENA  = 1048576;           // u16 per sample
constexpr size_t XT_OFF = 0;                 // [256][2048]
constexpr size_t A1_OFF = 524288;            // [256][1024]
constexpr size_t A2_OFF = 786432;            // [256][512]
constexpr size_t A3_OFF = 917504;            // [256][256]
constexpr size_t A4_OFF = 983040;            // [256][128]
constexpr size_t BAR_BYTE_OFF = (size_t)64 * ARENA * 2;  // 128 MiB

// 8-block per-sample generation barrier. Cross-XCD safe: __threadfence()
// (agent acq_rel: wbL2/invL2) + agent-scope atomics. State zeroed by
// hipMemsetAsync each launch -> deterministic.
DEVINL void gbar(unsigned* cnt, unsigned* gen)
{
    __syncthreads();
    if (threadIdx.x == 0) {
        unsigned g = __hip_atomic_load(gen, __ATOMIC_RELAXED, __HIP_MEMORY_SCOPE_AGENT);
        __threadfence();   // release: prior stores visible device-wide
        unsigned v = __hip_atomic_fetch_add(cnt, 1u, __ATOMIC_RELAXED, __HIP_MEMORY_SCOPE_AGENT);
        if (v == 7u) {
            __hip_atomic_store(cnt, 0u, __ATOMIC_RELAXED, __HIP_MEMORY_SCOPE_AGENT);
            __hip_atomic_store(gen, g + 1u, __ATOMIC_RELEASE, __HIP_MEMORY_SCOPE_AGENT);
        } else {
            while (__hip_atomic_load(gen, __ATOMIC_ACQUIRE, __HIP_MEMORY_SCOPE_AGENT) == g)
                __builtin_amdgcn_s_sleep(8);
        }
        __threadfence();   // acquire: invalidate stale cached lines
    }
    __syncthreads();
}

// R7's proven BN=256 GEMM body: 4 waves, each 64x64; B via global_load_lds
// (linear LDS, slot-XOR swizzle on pre-swizzled global source); A reg-staged.
// Writes Y rows [n][M] bf16 through an LDS re-layout epilogue.
DEVINL void gemm_bn256(const float* __restrict__ Wfull,      // + b*M*K
                       const float* __restrict__ biasb,      // + b*M
                       const unsigned short* __restrict__ xb,// [256][K]
                       unsigned short* __restrict__ yb,      // [256][M]
                       const int M, const int K, const int m0,
                       unsigned short* pool, const int tid)
{
    unsigned short* sA = pool;
    unsigned short* sB = pool + 64 * PA;

    const int lane = tid & 63;
    const int wid  = tid >> 6;
    const int wn   = wid * 64;
    const int fr   = lane & 15;
    const int fo   = (lane >> 4) * 8;

    const int am = tid >> 2, ac = (tid & 3) * 8;
    const float* Wb = Wfull + (size_t)(m0 + am) * K + ac;

    const int grow = wid * 64 + (lane >> 2);
    const int gchk = ((lane & 3) ^ ((lane >> 3) & 3)) * 8;
    const int bslot = ((lane >> 4) ^ ((fr >> 1) & 3)) * 8;

    const int NT = K / BK;

    float4 aS[2];

#define LOADA(k0) { aS[0] = *(const float4*)(Wb + (k0)); \
                    aS[1] = *(const float4*)(Wb + (k0) + 4); }
#define STOREA()  { ushort4 p0, p1; \
        p0.x = f2bf(aS[0].x); p0.y = f2bf(aS[0].y); p0.z = f2bf(aS[0].z); p0.w = f2bf(aS[0].w); \
        p1.x = f2bf(aS[1].x); p1.y = f2bf(aS[1].y); p1.z = f2bf(aS[1].z); p1.w = f2bf(aS[1].w); \
        *(ushort4*)&sA[am * PA + ac]     = p0; \
        *(ushort4*)&sA[am * PA + ac + 4] = p1; }
#define GLOADB(k0, bufofs) { \
    _Pragma("unroll") for (int i = 0; i < 4; ++i) { \
        const unsigned short* src_ = xb + (size_t)(grow + i * 16) * K + (k0) + gchk; \
        const unsigned short* dst_ = sB + (bufofs) + (wid * 64 + i * 16) * 32; \
        __builtin_amdgcn_global_load_lds( \
            (const __attribute__((address_space(1))) void*)src_, \
            (__attribute__((address_space(3))) void*)dst_, 16, 0, 0); } }

    f32x4 acc[4][4] = {};

    LOADA(0)
    GLOADB(0, 0)
    STOREA()
    __syncthreads();

#pragma unroll 1
    for (int t = 0; t < NT; ++t) {
        const int pr = (t & 1) * (256 * 32);
        const int pw = ((t + 1) & 1) * (256 * 32);
        if (t + 1 < NT) { LOADA((t + 1) * BK) GLOADB((t + 1) * BK, pw) }

        bf16x8 af[4], bf[4];
#pragma unroll
        for (int i = 0; i < 4; ++i)
            af[i] = *(const bf16x8*)&sA[(i * 16 + fr) * PA + fo];
#pragma unroll
        for (int i = 0; i < 4; ++i)
            bf[i] = *(const bf16x8*)&sB[pr + (wn + i * 16 + fr) * 32 + bslot];

        asm volatile("s_waitcnt lgkmcnt(0)" ::: "memory");
        __builtin_amdgcn_s_barrier();

        if (t + 1 < NT) STOREA()   // waits A loads only (issued before B gloads)

#pragma unroll
        for (int mi = 0; mi < 4; ++mi)
#pragma unroll
            for (int ni = 0; ni < 4; ++ni)
                acc[mi][ni] = __builtin_amdgcn_mfma_f32_16x16x32_bf16(af[mi], bf[ni], acc[mi][ni], 0, 0, 0);

        __syncthreads();   // B gloads for t+1 landed; sA writes visible
    }
#undef LOADA
#undef STOREA
#undef GLOADB

    // Epilogue: bias+sigmoid+pack -> LDS [128][72] -> 128B-contiguous row stores.
    const int hi4 = (lane >> 4) * 4;
#pragma unroll 1
    for (int ph = 0; ph < 2; ++ph) {
        if ((wn >> 7) == ph) {
#pragma unroll
            for (int mi = 0; mi < 4; ++mi) {
#pragma unroll
                for (int ni = 0; ni < 4; ++ni) {
                    const int r  = (wn & 127) + ni * 16 + fr;
                    const int mb = mi * 16 + hi4;
                    f32x4 v = acc[mi][ni];
                    ushort4 o;
#pragma unroll
                    for (int q = 0; q < 4; ++q) {
                        float yv = v[q] + biasb[m0 + mb + q];
                        yv = 1.0f / (1.0f + __expf(-yv));
                        ((unsigned short*)&o)[q] = f2bf(yv);
                    }
                    *(ushort4*)&pool[r * 72 + mb] = o;
                }
            }
        }
        __syncthreads();
        const int r = tid >> 3;
        const int c = (tid & 7) * 8;
#pragma unroll
        for (int it = 0; it < 4; ++it) {
            const int rr = r + it * 32;
            uint4 v = *(const uint4*)&pool[rr * 72 + c];
            *(uint4*)&yb[(size_t)(ph * 128 + rr) * M + m0 + c] = v;
        }
        __syncthreads();
    }
}

// ---------------------------------------------------------------------------
// Fully fused network: 512 blocks = 64 samples x 8 slices. All deps are
// intra-sample -> 8-block spin barrier. Residency by construction:
// launch_bounds(256,4) caps VGPR at 128 -> 4 blocks/CU capacity (1024 slots
// >= 512); LDS 37.9KB -> fits 4/CU. No launch boundaries, no xpose kernel,
// samples de-phase across layers (smooth HBM demand).
__global__ __launch_bounds__(256, 4)
void fused_net(const float* __restrict__ x,
               const float* __restrict__ w1, const float* __restrict__ b1,
               const float* __restrict__ w2, const float* __restrict__ b2,
               const float* __restrict__ w3, const float* __restrict__ b3,
               const float* __restrict__ w4, const float* __restrict__ b4,
               const float* __restrict__ w5, const float* __restrict__ b5,
               float* __restrict__ out, unsigned short* __restrict__ act,
               unsigned* __restrict__ bar)
{
    __shared__ __align__(128) unsigned char smem_raw[64 * PA * 2 + 2 * 256 * 32 * 2];
    unsigned short* pool = (unsigned short*)smem_raw;

    const int g = blockIdx.x;
    const int b = g >> 3;
    const int s = g & 7;
    const int tid = threadIdx.x;

    unsigned short* arena = act + (size_t)b * ARENA;
    unsigned* cnt = bar + b * 64;
    unsigned* gen = cnt + 1;

    // ---- P0: transpose+convert k-slice [s*256, s*256+256) of x[b] -> xT[b]
    {
        float (*sh)[65] = (float(*)[65])smem_raw;
        const int r  = tid >> 4;
        const int c4 = (tid & 15) * 4;
#pragma unroll 1
        for (int kt = 0; kt < 4; ++kt) {
#pragma unroll 1
            for (int nt = 0; nt < 4; ++nt) {
                const int k0 = s * 256 + kt * 64, n0 = nt * 64;
                const float* xb = x + ((size_t)b * 2048 + k0) * 256 + n0;
#pragma unroll
                for (int i = 0; i < 4; ++i) {
                    float4 v = *(const float4*)(xb + (size_t)(r + 16 * i) * 256 + c4);
                    sh[r + 16 * i][c4 + 0] = v.x;
                    sh[r + 16 * i][c4 + 1] = v.y;
                    sh[r + 16 * i][c4 + 2] = v.z;
                    sh[r + 16 * i][c4 + 3] = v.w;
                }
                __syncthreads();
#pragma unroll
                for (int i = 0; i < 4; ++i) {
                    const int rr = r + 16 * i;
                    ushort4 o;
                    o.x = f2bf(sh[c4 + 0][rr]);
                    o.y = f2bf(sh[c4 + 1][rr]);
                    o.z = f2bf(sh[c4 + 2][rr]);
                    o.w = f2bf(sh[c4 + 3][rr]);
                    *(ushort4*)(arena + XT_OFF + (size_t)(n0 + rr) * 2048 + k0 + c4) = o;
                }
                __syncthreads();
            }
        }
    }
    gbar(cnt, gen);

    // ---- P1: L1 (M=1024, K=2048): two 64-row m-slices per block
    gemm_bn256(w1 + (size_t)b * 1024 * 2048, b1 + (size_t)b * 1024,
               arena + XT_OFF, arena + A1_OFF, 1024, 2048, s * 64, pool, tid);
    gemm_bn256(w1 + (size_t)b * 1024 * 2048, b1 + (size_t)b * 1024,
               arena + XT_OFF, arena + A1_OFF, 1024, 2048, (s + 8) * 64, pool, tid);
    gbar(cnt, gen);

    // ---- P2: L2 (M=512, K=1024)
    gemm_bn256(w2 + (size_t)b * 512 * 1024, b2 + (size_t)b * 512,
               arena + A1_OFF, arena + A2_OFF, 512, 1024, s * 64, pool, tid);
    gbar(cnt, gen);

    // ---- P3: L3 (M=256, K=512): slices 0..3 busy
    if (s < 4)
        gemm_bn256(w3 + (size_t)b * 256 * 512, b3 + (size_t)b * 256,
                   arena + A2_OFF, arena + A3_OFF, 256, 512, s * 64, pool, tid);
    gbar(cnt, gen);

    // ---- P4: L4 (M=128, K=256): slices 0..1 busy
    if (s < 2)
        gemm_bn256(w4 + (size_t)b * 128 * 256, b4 + (size_t)b * 128,
                   arena + A3_OFF, arena + A4_OFF, 128, 256, s * 64, pool, tid);
    gbar(cnt, gen);

    // ---- P5: L5 (M=1): out[b][n] = dot(act4[n], w5[b]) + b5[b]
    if (tid < 32) {
        const int n = s * 32 + tid;
        const unsigned short* row = arena + A4_OFF + (size_t)n * 128;
        const float* w = w5 + (size_t)b * 128;
        float accv = b5[b];
#pragma unroll
        for (int k = 0; k < 128; k += 8) {
            uint4 v = *(const uint4*)(row + k);
            accv += bf2f((unsigned short)(v.x & 0xffff)) * w[k+0];
            accv += bf2f((unsigned short)(v.x >> 16))    * w[k+1];
            accv += bf2f((unsigned short)(v.y & 0xffff)) * w[k+2];
            accv += bf2f((unsigned short)(v.y >> 16))    * w[k+3];
            accv += bf2f((unsigned short)(v.z & 0xffff)) * w[k+4];
            accv += bf2f((unsigned short)(v.z >> 16))    * w[k+5];
            accv += bf2f((unsigned short)(v.w & 0xffff)) * w[k+6];
            accv += bf2f((unsigned short)(v.w >> 16))    * w[k+7];
        }
        out[b * NSP + n] = accv;
    }
}

extern "C" void kernel_launch(void* const* d_in, const int* in_sizes, int n_in,
                              void* d_out, int out_size, void* d_ws, size_t ws_size,
                              hipStream_t stream)
{
    const float* x  = (const float*)d_in[0];
    const float* w1 = (const float*)d_in[1];
    const float* b1 = (const float*)d_in[2];
    const float* w2 = (const float*)d_in[3];
    const float* b2 = (const float*)d_in[4];
    const float* w3 = (const float*)d_in[5];
    const float* b3 = (const float*)d_in[6];
    const float* w4 = (const float*)d_in[7];
    const float* b4 = (const float*)d_in[8];
    const float* w5 = (const float*)d_in[9];
    const float* b5 = (const float*)d_in[10];

    unsigned short* act = (unsigned short*)d_ws;
    unsigned* bar = (unsigned*)((char*)d_ws + BAR_BYTE_OFF);

    // Zero barrier state (64 groups x 256B). Capture-legal async memset.
    hipMemsetAsync((void*)bar, 0, 64 * 256, stream);

    fused_net<<<dim3(512), dim3(256), 0, stream>>>(
        x, w1, b1, w2, b2, w3, b3, w4, b4, w5, b5,
        (float*)d_out, act, bar);
}

// Round 9
// 653.822 us; speedup vs baseline: 1.2508x; 1.2508x over previous
//
#include <hip/hip_runtime.h>
#include <hip/hip_bf16.h>
#include <cstdint>

#define DEVINL __device__ __forceinline__

typedef __attribute__((ext_vector_type(8))) short bf16x8;
typedef __attribute__((ext_vector_type(4))) float f32x4;

DEVINL unsigned short f2bf(float f) {
    union { float f; unsigned u; } v; v.f = f;
    unsigned r = v.u + 0x7fffu + ((v.u >> 16) & 1u);   // RNE
    return (unsigned short)(r >> 16);
}
DEVINL float bf2f(unsigned short h) {
    union { unsigned u; float f; } v; v.u = ((unsigned)h) << 16;
    return v.f;
}

constexpr int BM = 64, BN = 256, BK = 32;
constexpr int PA  = 40;    // sA pitch (u16): 80B rows, uniform bank spread
constexpr int NSP = 256;   // H*W
constexpr int BUF = 256 * 32;  // one sB buffer (u16)

// ---------------------------------------------------------------------------
// Transpose + bf16 convert: x[b][2048][256] f32 -> xT[b][256][2048] bf16.
__global__ __launch_bounds__(256)
void xpose(const float* __restrict__ x, unsigned short* __restrict__ xT)
{
    __shared__ float sh[64][65];
    const int b   = blockIdx.y;
    const int kt  = blockIdx.x & 31;     // 2048/64
    const int ntb = blockIdx.x >> 5;     // 256/64
    const int k0 = kt * 64, n0 = ntb * 64;

    const int r = threadIdx.x >> 4;          // 0..15
    const int c = (threadIdx.x & 15) * 4;    // 0..60

    const float* xb = x + ((size_t)b * 2048 + k0) * 256 + n0;
#pragma unroll
    for (int i = 0; i < 4; ++i) {
        float4 v = *(const float4*)(xb + (size_t)(r + 16 * i) * 256 + c);
        sh[r + 16 * i][c + 0] = v.x;
        sh[r + 16 * i][c + 1] = v.y;
        sh[r + 16 * i][c + 2] = v.z;
        sh[r + 16 * i][c + 3] = v.w;
    }
    __syncthreads();
#pragma unroll
    for (int i = 0; i < 4; ++i) {
        const int rr = r + 16 * i;           // n within tile
        ushort4 o;
        o.x = f2bf(sh[c + 0][rr]);
        o.y = f2bf(sh[c + 1][rr]);
        o.z = f2bf(sh[c + 2][rr]);
        o.w = f2bf(sh[c + 3][rr]);
        *(ushort4*)(xT + ((size_t)b * NSP + n0 + rr) * 2048 + k0 + c) = o;
    }
}

// ---------------------------------------------------------------------------
// Y^T[b][n][m] = sigmoid( sum_k W[b][m][k]*XT[b][n][k] + bias[b][m] ), bf16 out.
// R7 structure (4 waves, each 64x64; B via global_load_lds with slot-XOR
// swizzle; A reg-staged) + THIS ROUND: depth-2 A register prefetch (two named
// sets) and counted-vmcnt bar2 (raw s_barrier, never vmcnt(0) in steady state).
// Per-step issue order: GLOADB(t+1) [4 ops] then LOADA(t+2) [2 ops].
// FIFO vmcnt: STOREA's compiler wait completes A(t+1) (oldest); bar2 waits
// vmcnt(2) = B(t+1) landed, A(t+2) still in flight.
__global__ __launch_bounds__(256, 4)
void fc_gemm(const float* __restrict__ Wt, const float* __restrict__ bias,
             const unsigned short* __restrict__ X, unsigned short* __restrict__ Yt,
             int M, int K)
{
    const int b  = blockIdx.x;
    const int m0 = blockIdx.y * BM;

    // pool: sA [64][40] u16 + sB 2 x [256][32] u16. Epilogue reuses as [128][72].
    __shared__ __align__(128) unsigned short pool[64 * PA + 2 * BUF];
    unsigned short* sA = pool;
    unsigned short* sB = pool + 64 * PA;

    const int tid  = threadIdx.x;
    const int lane = tid & 63;
    const int wid  = tid >> 6;            // 0..3
    const int wn   = wid * 64;            // wave's n-offset
    const int fr   = lane & 15;
    const int fo   = (lane >> 4) * 8;

    // A staging: 64x32 f32, thread owns row tid>>2, cols (tid&3)*8 .. +8
    const int am = tid >> 2, ac = (tid & 3) * 8;
    const float* Wb = Wt + (size_t)b * M * K + (size_t)m0 * K + (size_t)am * K + ac;

    // B gload source params: per-lane row/chunk with slot-XOR pre-swizzle
    const int grow = wid * 64 + (lane >> 2);                 // + i*16
    const int gchk = ((lane & 3) ^ ((lane >> 3) & 3)) * 8;   // elem offset in row
    const unsigned short* Xb = X + (size_t)b * NSP * K;

    // B frag read slot (involution of the write swizzle): uniform 8 words/bank
    const int bslot = ((lane >> 4) ^ ((fr >> 1) & 3)) * 8;

    const int NT = K / BK;   // 64/32/16/8 (even)

    float4 aSa[2], aSb[2];   // two named A staging sets (depth-2 prefetch)

#define LOADA2(dst, k0) { dst[0] = *(const float4*)(Wb + (k0)); \
                          dst[1] = *(const float4*)(Wb + (k0) + 4); }
#define STOREA(src)  { ushort4 p0, p1; \
        p0.x = f2bf(src[0].x); p0.y = f2bf(src[0].y); p0.z = f2bf(src[0].z); p0.w = f2bf(src[0].w); \
        p1.x = f2bf(src[1].x); p1.y = f2bf(src[1].y); p1.z = f2bf(src[1].z); p1.w = f2bf(src[1].w); \
        *(ushort4*)&sA[am * PA + ac]     = p0; \
        *(ushort4*)&sA[am * PA + ac + 4] = p1; }
#define GLOADB(k0, bufofs) { \
    _Pragma("unroll") for (int i = 0; i < 4; ++i) { \
        const unsigned short* src_ = Xb + (size_t)(grow + i * 16) * K + (k0) + gchk; \
        const unsigned short* dst_ = sB + (bufofs) + (wid * 64 + i * 16) * 32; \
        __builtin_amdgcn_global_load_lds( \
            (const __attribute__((address_space(1))) void*)src_, \
            (__attribute__((address_space(3))) void*)dst_, 16, 0, 0); } }

    f32x4 acc[4][4] = {};

    // Prologue: B(0) -> buf0; A(0) -> aSa (stored now); A(1) -> aSb (in flight).
    GLOADB(0, 0)
    LOADA2(aSa, 0)
    LOADA2(aSb, BK)
    STOREA(aSa)   // compiler waits A(0) (FIFO => B(0) also landed)
    asm volatile("s_waitcnt lgkmcnt(0)" ::: "memory");
    __builtin_amdgcn_s_barrier();

    // Step t: read tile t from sA / sB[t&1]; issue B(t+1)->other buf and
    // A(t+2)->FILL set; after bar1 store CONS set (= A(t+1)); MFMA; bar2 with
    // counted vmcnt so A(t+2) stays in flight across the barrier.
#define KSTEP(t_, CONS, FILL) { \
    const int tt = (t_); \
    const int pr = (tt & 1) * BUF; \
    const int pw = ((tt + 1) & 1) * BUF; \
    if (tt + 1 < NT) GLOADB((tt + 1) * BK, pw) \
    if (tt + 2 < NT) LOADA2(FILL, (tt + 2) * BK) \
    bf16x8 af[4], bfv[4]; \
    _Pragma("unroll") for (int i = 0; i < 4; ++i) \
        af[i] = *(const bf16x8*)&sA[(i * 16 + fr) * PA + fo]; \
    _Pragma("unroll") for (int i = 0; i < 4; ++i) \
        bfv[i] = *(const bf16x8*)&sB[pr + (wn + i * 16 + fr) * 32 + bslot]; \
    asm volatile("s_waitcnt lgkmcnt(0)" ::: "memory"); \
    __builtin_amdgcn_s_barrier();                      /* bar1: reads done */ \
    if (tt + 1 < NT) STOREA(CONS)                      /* waits A(t+1) only */ \
    _Pragma("unroll") for (int mi = 0; mi < 4; ++mi) \
        _Pragma("unroll") for (int ni = 0; ni < 4; ++ni) \
            acc[mi][ni] = __builtin_amdgcn_mfma_f32_16x16x32_bf16(af[mi], bfv[ni], acc[mi][ni], 0, 0, 0); \
    if (tt + 2 < NT) { asm volatile("s_waitcnt vmcnt(2)" ::: "memory"); } \
    else             { asm volatile("s_waitcnt vmcnt(0)" ::: "memory"); } \
    asm volatile("s_waitcnt lgkmcnt(0)" ::: "memory"); \
    __builtin_amdgcn_s_barrier();                      /* bar2: tile t+1 ready */ \
}

#pragma unroll 1
    for (int t = 0; t < NT; t += 2) {
        KSTEP(t,     aSb, aSa)   // consume A(t+1)=aSb, fill aSa with A(t+2)
        KSTEP(t + 1, aSa, aSb)
    }
#undef KSTEP
#undef LOADA2
#undef STOREA
#undef GLOADB

    // ---- Epilogue: bias+sigmoid+pack -> LDS [128][72] -> 128B-contiguous rows.
    const int hi4 = (lane >> 4) * 4;
#pragma unroll 1
    for (int ph = 0; ph < 2; ++ph) {
        if ((wn >> 7) == ph) {
#pragma unroll
            for (int mi = 0; mi < 4; ++mi) {
#pragma unroll
                for (int ni = 0; ni < 4; ++ni) {
                    const int r  = (wn & 127) + ni * 16 + fr;   // n within phase
                    const int mb = mi * 16 + hi4;               // m within block
                    f32x4 v = acc[mi][ni];
                    ushort4 o;
#pragma unroll
                    for (int q = 0; q < 4; ++q) {
                        float yv = v[q] + bias[(size_t)b * M + m0 + mb + q];
                        yv = 1.0f / (1.0f + __expf(-yv));
                        ((unsigned short*)&o)[q] = f2bf(yv);
                    }
                    *(ushort4*)&pool[r * 72 + mb] = o;
                }
            }
        }
        __syncthreads();
        const int r = tid >> 3;             // 0..31
        const int c = (tid & 7) * 8;        // 0..56
#pragma unroll
        for (int it = 0; it < 4; ++it) {
            const int rr = r + it * 32;
            uint4 v = *(const uint4*)&pool[rr * 72 + c];
            *(uint4*)&Yt[((size_t)b * NSP + ph * 128 + rr) * M + m0 + c] = v;
        }
        __syncthreads();
    }
}

// Layer 5: out[b][n] = sum_k act4T[b][n][k] * w5[b][k] + b5[b]   (no sigmoid)
__global__ void fc_final(const unsigned short* __restrict__ A4,
                         const float* __restrict__ W5,
                         const float* __restrict__ B5,
                         float* __restrict__ out)
{
    const int b = blockIdx.x;
    const int t = threadIdx.x;  // 0..255 spatial
    const unsigned short* row = A4 + ((size_t)b * NSP + t) * 128;
    const float* w = W5 + (size_t)b * 128;
    float acc = B5[b];
#pragma unroll
    for (int k = 0; k < 128; k += 8) {
        uint4 v = *(const uint4*)(row + k);
        acc += bf2f((unsigned short)(v.x & 0xffff)) * w[k+0];
        acc += bf2f((unsigned short)(v.x >> 16))    * w[k+1];
        acc += bf2f((unsigned short)(v.y & 0xffff)) * w[k+2];
        acc += bf2f((unsigned short)(v.y >> 16))    * w[k+3];
        acc += bf2f((unsigned short)(v.z & 0xffff)) * w[k+4];
        acc += bf2f((unsigned short)(v.z >> 16))    * w[k+5];
        acc += bf2f((unsigned short)(v.w & 0xffff)) * w[k+6];
        acc += bf2f((unsigned short)(v.w >> 16))    * w[k+7];
    }
    out[b * NSP + t] = acc;
}

extern "C" void kernel_launch(void* const* d_in, const int* in_sizes, int n_in,
                              void* d_out, int out_size, void* d_ws, size_t ws_size,
                              hipStream_t stream)
{
    const float* x  = (const float*)d_in[0];
    const float* w1 = (const float*)d_in[1];
    const float* b1 = (const float*)d_in[2];
    const float* w2 = (const float*)d_in[3];
    const float* b2 = (const float*)d_in[4];
    const float* w3 = (const float*)d_in[5];
    const float* b3 = (const float*)d_in[6];
    const float* w4 = (const float*)d_in[7];
    const float* b4 = (const float*)d_in[8];
    const float* w5 = (const float*)d_in[9];
    const float* b5 = (const float*)d_in[10];

    unsigned short* ws0 = (unsigned short*)d_ws;

    // u16-element offsets. xT dead after L1 -> act2/3/4 reuse its region.
    const size_t XT = (size_t)64 * 256 * 2048;  // 33.55M u16 (67.1 MB)
    unsigned short* xT   = ws0;
    unsigned short* act1 = ws0 + XT;
    unsigned short* act2 = ws0;
    unsigned short* act3 = ws0 + (size_t)64 * 256 * 512;
    unsigned short* act4 = ws0 + (size_t)64 * 256 * (512 + 256);

    xpose<<<dim3(128, 64), dim3(256), 0, stream>>>(x, xT);
    fc_gemm<<<dim3(64, 16), dim3(256), 0, stream>>>(w1, b1, xT,   act1, 1024, 2048);
    fc_gemm<<<dim3(64,  8), dim3(256), 0, stream>>>(w2, b2, act1, act2,  512, 1024);
    fc_gemm<<<dim3(64,  4), dim3(256), 0, stream>>>(w3, b3, act2, act3,  256,  512);
    fc_gemm<<<dim3(64,  2), dim3(256), 0, stream>>>(w4, b4, act3, act4,  128,  256);
    fc_final<<<dim3(64), dim3(256), 0, stream>>>(act4, w5, b5, (float*)d_out);
}

// Round 10
// 357.678 us; speedup vs baseline: 2.2865x; 1.8280x over previous
//
#include <hip/hip_runtime.h>
#include <hip/hip_bf16.h>
#include <cstdint>

#define DEVINL __device__ __forceinline__

typedef __attribute__((ext_vector_type(8))) short bf16x8;
typedef __attribute__((ext_vector_type(4))) float f32x4;

DEVINL unsigned short f2bf(float f) {
    union { float f; unsigned u; } v; v.f = f;
    unsigned r = v.u + 0x7fffu + ((v.u >> 16) & 1u);   // RNE
    return (unsigned short)(r >> 16);
}
DEVINL float bf2f(unsigned short h) {
    union { unsigned u; float f; } v; v.u = ((unsigned)h) << 16;
    return v.f;
}

constexpr int BM = 64, BN = 256, BK = 32;
constexpr int NSP   = 256;        // H*W
constexpr int SABUF = 64 * 32;    // one sA buffer (u16)
constexpr int SBUF  = 256 * 32;   // one sB buffer (u16)

// ---------------------------------------------------------------------------
// Transpose + bf16 convert: x[b][2048][256] f32 -> xT[b][256][2048] bf16.
__global__ __launch_bounds__(256)
void xpose(const float* __restrict__ x, unsigned short* __restrict__ xT)
{
    __shared__ float sh[64][65];
    const int b   = blockIdx.y;
    const int kt  = blockIdx.x & 31;     // 2048/64
    const int ntb = blockIdx.x >> 5;     // 256/64
    const int k0 = kt * 64, n0 = ntb * 64;

    const int r = threadIdx.x >> 4;          // 0..15
    const int c = (threadIdx.x & 15) * 4;    // 0..60

    const float* xb = x + ((size_t)b * 2048 + k0) * 256 + n0;
#pragma unroll
    for (int i = 0; i < 4; ++i) {
        float4 v = *(const float4*)(xb + (size_t)(r + 16 * i) * 256 + c);
        sh[r + 16 * i][c + 0] = v.x;
        sh[r + 16 * i][c + 1] = v.y;
        sh[r + 16 * i][c + 2] = v.z;
        sh[r + 16 * i][c + 3] = v.w;
    }
    __syncthreads();
#pragma unroll
    for (int i = 0; i < 4; ++i) {
        const int rr = r + 16 * i;           // n within tile
        ushort4 o;
        o.x = f2bf(sh[c + 0][rr]);
        o.y = f2bf(sh[c + 1][rr]);
        o.z = f2bf(sh[c + 2][rr]);
        o.w = f2bf(sh[c + 3][rr]);
        *(ushort4*)(xT + ((size_t)b * NSP + n0 + rr) * 2048 + k0 + c) = o;
    }
}

// ---------------------------------------------------------------------------
// Y^T[b][n][m] = sigmoid( sum_k W[b][m][k]*XT[b][n][k] + bias[b][m] ), bf16 out.
// R7 base (4 waves x 64x64; B via global_load_lds + slot-XOR swizzle) with:
//  - sA double-buffered linear [2][64][32] (64B rows: uniform banks, no pad)
//    -> ONE barrier per K-step (bar1 eliminated)
//  - T14 issue-early/store-late: LOADA(t+1) at step top, STOREA after MFMA
//    (~full step of HBM-latency cover), compiler-inserted waits ONLY.
__global__ __launch_bounds__(256, 4)
void fc_gemm(const float* __restrict__ Wt, const float* __restrict__ bias,
             const unsigned short* __restrict__ X, unsigned short* __restrict__ Yt,
             int M, int K)
{
    const int b  = blockIdx.x;
    const int m0 = blockIdx.y * BM;

    // pool: 2 x sA (2048 u16) + 2 x sB (8192 u16) = 20480 u16 = 40960 B.
    // Epilogue reuses pool as [128][72] u16 (9216).
    __shared__ __align__(128) unsigned short pool[2 * SABUF + 2 * SBUF];
    unsigned short* sA = pool;
    unsigned short* sB = pool + 2 * SABUF;

    const int tid  = threadIdx.x;
    const int lane = tid & 63;
    const int wid  = tid >> 6;            // 0..3
    const int wn   = wid * 64;            // wave's n-offset
    const int fr   = lane & 15;
    const int fo   = (lane >> 4) * 8;     // k-chunk offset (u16)

    // A staging: 64x32 f32, thread owns row tid>>2, one 16B chunk (tid&3)*8
    const int am = tid >> 2, ac = (tid & 3) * 8;
    const float* Wb = Wt + (size_t)b * M * K + (size_t)m0 * K + (size_t)am * K + ac;

    // B gload source: per-lane row/chunk with slot-XOR pre-swizzle (proven R7)
    const int grow = wid * 64 + (lane >> 2);                 // + i*16
    const int gchk = ((lane & 3) ^ ((lane >> 3) & 3)) * 8;   // elem offset in row
    const unsigned short* Xb = X + (size_t)b * NSP * K;

    // B frag read slot (involution of the write swizzle)
    const int bslot = ((lane >> 4) ^ ((fr >> 1) & 3)) * 8;

    const int NT = K / BK;   // 64/32/16/8

    float4 aS[2];            // single A staging set (issue-early / store-late)

#define LOADA(k0) { aS[0] = *(const float4*)(Wb + (k0)); \
                    aS[1] = *(const float4*)(Wb + (k0) + 4); }
#define STOREA(p) { uint4 w_; \
        w_.x = (unsigned)f2bf(aS[0].x) | ((unsigned)f2bf(aS[0].y) << 16); \
        w_.y = (unsigned)f2bf(aS[0].z) | ((unsigned)f2bf(aS[0].w) << 16); \
        w_.z = (unsigned)f2bf(aS[1].x) | ((unsigned)f2bf(aS[1].y) << 16); \
        w_.w = (unsigned)f2bf(aS[1].z) | ((unsigned)f2bf(aS[1].w) << 16); \
        *(uint4*)&sA[(p) * SABUF + am * 32 + ac] = w_; }
#define GLOADB(k0, p) { \
    _Pragma("unroll") for (int i = 0; i < 4; ++i) { \
        const unsigned short* src_ = Xb + (size_t)(grow + i * 16) * K + (k0) + gchk; \
        const unsigned short* dst_ = sB + (p) * SBUF + (wid * 64 + i * 16) * 32; \
        __builtin_amdgcn_global_load_lds( \
            (const __attribute__((address_space(1))) void*)src_, \
            (__attribute__((address_space(3))) void*)dst_, 16, 0, 0); } }

    f32x4 acc[4][4] = {};

    // Prologue: B(0) + A(0) -> buffers 0; single drain.
    GLOADB(0, 0)
    LOADA(0)
    STOREA(0)
    __syncthreads();

#pragma unroll 1
    for (int t = 0; t < NT; ++t) {
        const int p = t & 1;
        if (t + 1 < NT) { LOADA((t + 1) * BK) GLOADB((t + 1) * BK, p ^ 1) }

        bf16x8 af[4], bfv[4];
#pragma unroll
        for (int i = 0; i < 4; ++i)
            af[i] = *(const bf16x8*)&sA[p * SABUF + (i * 16 + fr) * 32 + fo];
#pragma unroll
        for (int i = 0; i < 4; ++i)
            bfv[i] = *(const bf16x8*)&sB[p * SBUF + (wn + i * 16 + fr) * 32 + bslot];

#pragma unroll
        for (int mi = 0; mi < 4; ++mi)
#pragma unroll
            for (int ni = 0; ni < 4; ++ni)
                acc[mi][ni] = __builtin_amdgcn_mfma_f32_16x16x32_bf16(af[mi], bfv[ni], acc[mi][ni], 0, 0, 0);

        if (t + 1 < NT) STOREA(p ^ 1)   // A(t+1) had ~full step of cover

        __syncthreads();                // single per-step barrier: B landed,
                                        // sA[p^1] visible, all reads done
    }
#undef LOADA
#undef STOREA
#undef GLOADB

    // ---- Epilogue: bias+sigmoid+pack -> LDS [128][72] -> 128B-contiguous rows.
    const int hi4 = (lane >> 4) * 4;
#pragma unroll 1
    for (int ph = 0; ph < 2; ++ph) {
        if ((wn >> 7) == ph) {
#pragma unroll
            for (int mi = 0; mi < 4; ++mi) {
#pragma unroll
                for (int ni = 0; ni < 4; ++ni) {
                    const int r  = (wn & 127) + ni * 16 + fr;   // n within phase
                    const int mb = mi * 16 + hi4;               // m within block
                    f32x4 v = acc[mi][ni];
                    ushort4 o;
#pragma unroll
                    for (int q = 0; q < 4; ++q) {
                        float yv = v[q] + bias[(size_t)b * M + m0 + mb + q];
                        yv = 1.0f / (1.0f + __expf(-yv));
                        ((unsigned short*)&o)[q] = f2bf(yv);
                    }
                    *(ushort4*)&pool[r * 72 + mb] = o;
                }
            }
        }
        __syncthreads();
        const int r = tid >> 3;             // 0..31
        const int c = (tid & 7) * 8;        // 0..56
#pragma unroll
        for (int it = 0; it < 4; ++it) {
            const int rr = r + it * 32;
            uint4 v = *(const uint4*)&pool[rr * 72 + c];
            *(uint4*)&Yt[((size_t)b * NSP + ph * 128 + rr) * M + m0 + c] = v;
        }
        __syncthreads();
    }
}

// Layer 5: out[b][n] = sum_k act4T[b][n][k] * w5[b][k] + b5[b]   (no sigmoid)
__global__ void fc_final(const unsigned short* __restrict__ A4,
                         const float* __restrict__ W5,
                         const float* __restrict__ B5,
                         float* __restrict__ out)
{
    const int b = blockIdx.x;
    const int t = threadIdx.x;  // 0..255 spatial
    const unsigned short* row = A4 + ((size_t)b * NSP + t) * 128;
    const float* w = W5 + (size_t)b * 128;
    float acc = B5[b];
#pragma unroll
    for (int k = 0; k < 128; k += 8) {
        uint4 v = *(const uint4*)(row + k);
        acc += bf2f((unsigned short)(v.x & 0xffff)) * w[k+0];
        acc += bf2f((unsigned short)(v.x >> 16))    * w[k+1];
        acc += bf2f((unsigned short)(v.y & 0xffff)) * w[k+2];
        acc += bf2f((unsigned short)(v.y >> 16))    * w[k+3];
        acc += bf2f((unsigned short)(v.z & 0xffff)) * w[k+4];
        acc += bf2f((unsigned short)(v.z >> 16))    * w[k+5];
        acc += bf2f((unsigned short)(v.w & 0xffff)) * w[k+6];
        acc += bf2f((unsigned short)(v.w >> 16))    * w[k+7];
    }
    out[b * NSP + t] = acc;
}

extern "C" void kernel_launch(void* const* d_in, const int* in_sizes, int n_in,
                              void* d_out, int out_size, void* d_ws, size_t ws_size,
                              hipStream_t stream)
{
    const float* x  = (const float*)d_in[0];
    const float* w1 = (const float*)d_in[1];
    const float* b1 = (const float*)d_in[2];
    const float* w2 = (const float*)d_in[3];
    const float* b2 = (const float*)d_in[4];
    const float* w3 = (const float*)d_in[5];
    const float* b3 = (const float*)d_in[6];
    const float* w4 = (const float*)d_in[7];
    const float* b4 = (const float*)d_in[8];
    const float* w5 = (const float*)d_in[9];
    const float* b5 = (const float*)d_in[10];

    unsigned short* ws0 = (unsigned short*)d_ws;

    // u16-element offsets. xT dead after L1 -> act2/3/4 reuse its region.
    const size_t XT = (size_t)64 * 256 * 2048;  // 33.55M u16 (67.1 MB)
    unsigned short* xT   = ws0;
    unsigned short* act1 = ws0 + XT;
    unsigned short* act2 = ws0;
    unsigned short* act3 = ws0 + (size_t)64 * 256 * 512;
    unsigned short* act4 = ws0 + (size_t)64 * 256 * (512 + 256);

    xpose<<<dim3(128, 64), dim3(256), 0, stream>>>(x, xT);
    fc_gemm<<<dim3(64, 16), dim3(256), 0, stream>>>(w1, b1, xT,   act1, 1024, 2048);
    fc_gemm<<<dim3(64,  8), dim3(256), 0, stream>>>(w2, b2, act1, act2,  512, 1024);
    fc_gemm<<<dim3(64,  4), dim3(256), 0, stream>>>(w3, b3, act2, act3,  256,  512);
    fc_gemm<<<dim3(64,  2), dim3(256), 0, stream>>>(w4, b4, act3, act4,  128,  256);
    fc_final<<<dim3(64), dim3(256), 0, stream>>>(act4, w5, b5, (float*)d_out);
}